// Round 13
// baseline (29350.882 us; speedup 1.0000x reference)
//
#include <hip/hip_runtime.h>
#include <math.h>

#define L_SEQ 8192
#define I_DIM 256
#define H_DIM 2048
#define NWG0  64          // layer-0: 64 WGs x 32 rows (16 thr/row)
#define NWG1  128         // layer-1: 128 WGs x 16 rows (32 thr/row)
#define NWG   (NWG0 + NWG1)
#define TPB   512
#define RD    16          // h ring depth
#define RM    (RD - 1)
#define TLAG  11          // L0 throttle lag (checked every 4th step)

// ws (bytes): [0] runctr | [256..1024) bslots | [4096) h0 ring 16*2048 f32
//             | [4096+128K) h1 ring 16*2048 f32
//
// Base = round-12 (best: 24.7 ms). Tagged dataflow: published value =
// h + ctr(step), ctr = 4+8*((step>>4)&1), ring depth 16, valid iff |v-ctr|<=1;
// per-run slot re-init (slot0 = tagged h_0, slots 1..15 = 0.0f invalid);
// 0xAA poison and 0.0f fail both windows. Start barrier on monotone runctr.
// Ring-16 + throttle lag 11 every 4th step (safety margins proven r12).
// Weight arrays float4[...] constant-unrolled (AGPR-resident, VGPR=112 --
// DO NOT restructure).
//
// Round-13 diff (L1 only): PARALLEL dual-poll. Threads 0-255 poll the h0_t
// vector (2 contiguous granules each, pipelined dwordx4 pair) while threads
// 256-511 concurrently poll h1_{t-1}. One sync, then the full ih+hh dot.
// Removes the serialized RT(h0) + second sync from the h1 chain: step =
// max(RT_h0, T_h1+RT_h1) + dot + publish.

typedef float f32x4 __attribute__((ext_vector_type(4)));
typedef float f32x2 __attribute__((ext_vector_type(2)));

__device__ __forceinline__ void cstore1(float* p, float v) {
  asm volatile("global_store_dword %0, %1, off sc0 sc1" :: "v"(p), "v"(v) : "memory");
}
__device__ __forceinline__ void cstore2f(float* p, float a, float b) {
  f32x2 v; v.x = a; v.y = b;
  asm volatile("global_store_dwordx2 %0, %1, off sc0 sc1" :: "v"(p), "v"(v) : "memory");
}
__device__ __forceinline__ void cstore4f(float* p, float a, float b, float c, float d) {
  f32x4 v; v.x = a; v.y = b; v.z = c; v.w = d;
  asm volatile("global_store_dwordx4 %0, %1, off sc0 sc1" :: "v"(p), "v"(v) : "memory");
}
__device__ __forceinline__ void cstoreu(unsigned* p, unsigned v) {
  asm volatile("global_store_dword %0, %1, off sc0 sc1" :: "v"(p), "v"(v) : "memory");
}
__device__ __forceinline__ float cload1(const float* p) {
  float v;
  asm volatile("global_load_dword %0, %1, off sc0 sc1\n\ts_waitcnt vmcnt(0)"
               : "=v"(v) : "v"(p) : "memory");
  return v;
}
__device__ __forceinline__ unsigned cloadu(const unsigned* p) {
  unsigned v;
  asm volatile("global_load_dword %0, %1, off sc0 sc1\n\ts_waitcnt vmcnt(0)"
               : "=v"(v) : "v"(p) : "memory");
  return v;
}
__device__ __forceinline__ float4 cload4(const float* p) {
  float4 v;
  asm volatile("global_load_dwordx4 %0, %1, off sc0 sc1\n\ts_waitcnt vmcnt(0)"
               : "=v"(v) : "v"(p) : "memory");
  return v;
}
__device__ __forceinline__ void cload4x2(const float* p0, const float* p1, float4& a, float4& b) {
  asm volatile("global_load_dwordx4 %0, %2, off sc0 sc1\n\t"
               "global_load_dwordx4 %1, %3, off sc0 sc1\n\t"
               "s_waitcnt vmcnt(0)"
               : "=&v"(a), "=&v"(b) : "v"(p0), "v"(p1) : "memory");
}
__device__ __forceinline__ float4 ld4(const float* p) {   // weight load, opaque
  float4 v;
  asm volatile("global_load_dwordx4 %0, %1, off\n\ts_waitcnt vmcnt(0)"
               : "=v"(v) : "v"(p) : "memory");
  return v;
}
__device__ __forceinline__ float tagc(int step) {
  return 4.f + 8.f * (float)((step >> 4) & 1);
}
__device__ __forceinline__ bool ok4(float4 v, float c) {
  return __builtin_fabsf(v.x - c) <= 1.f && __builtin_fabsf(v.y - c) <= 1.f &&
         __builtin_fabsf(v.z - c) <= 1.f && __builtin_fabsf(v.w - c) <= 1.f;
}
__device__ __forceinline__ float4 poll4(const float* p, float c) {
  float4 v = cload4(p);
  while (!ok4(v, c)) { __builtin_amdgcn_s_sleep(1); v = cload4(p); }
  return make_float4(v.x - c, v.y - c, v.z - c, v.w - c);
}
// two contiguous granules (32B), same tag: pipelined pair, re-issue both on any-stale
__device__ __forceinline__ void poll8(const float* p, float c, float4& a, float4& b) {
  float4 u, v;
  cload4x2(p, p + 4, u, v);
  while (!(ok4(u, c) && ok4(v, c))) {
    __builtin_amdgcn_s_sleep(1);
    cload4x2(p, p + 4, u, v);
  }
  a = make_float4(u.x - c, u.y - c, u.z - c, u.w - c);
  b = make_float4(v.x - c, v.y - c, v.z - c, v.w - c);
}
__device__ __forceinline__ float tanh_fast(float v) {   // exact identity
  float e = __expf(2.f * v);
  return 1.f - 2.f / (e + 1.f);
}
__device__ __forceinline__ void start_barrier(unsigned* bslots, int wg, int tid, unsigned value) {
  __syncthreads();
  if (tid == 0) cstoreu(&bslots[wg], value);
  if (tid < NWG) {
    while ((int)(cloadu(&bslots[tid]) - value) < 0) __builtin_amdgcn_s_sleep(1);
  }
  __syncthreads();
}

__global__ __launch_bounds__(TPB, 2)
void rnn2_dualpoll(const float* __restrict__ x,
                   const float* __restrict__ Wih0, const float* __restrict__ Whh0,
                   const float* __restrict__ bih0, const float* __restrict__ bhh0,
                   const float* __restrict__ Wih1, const float* __restrict__ Whh1,
                   const float* __restrict__ bih1, const float* __restrict__ bhh1,
                   const float* __restrict__ Wfc,  const float* __restrict__ bfc,
                   float* __restrict__ out,
                   unsigned* __restrict__ runctr, unsigned* __restrict__ bslots,
                   float* __restrict__ h0s, float* __restrict__ h1s)
{
  const int wg  = blockIdx.x;
  const int tid = threadIdx.x;
  const int wv  = tid >> 6;
  __shared__ float4 lds4[2][1024];

  const unsigned runbase = cloadu(runctr);

  if (wg < NWG0) {
    // ---------------- layer 0: 32 rows/WG, 16 threads/row (= round 12) ----------------
    const int cg  = tid & 15;
    const int row = wg * 32 + (tid >> 4);
    float4 wihr[4], whhr[32];
    {
      const float* wr = Wih0 + (size_t)row * I_DIM + (cg << 2);
      #pragma unroll
      for (int k = 0; k < 4; ++k) wihr[k] = ld4(wr + (k << 6));
      const float* wr2 = Whh0 + (size_t)row * H_DIM + (cg << 2);
      #pragma unroll
      for (int k = 0; k < 32; ++k) whhr[k] = ld4(wr2 + (k << 6));
    }
    const float bias = bih0[row] + bhh0[row];

    {   // re-init all 16 ring slots of owned rows: slot0 = tagged h0_0 (=4.0)
      int sl = tid >> 5; int r = wg * 32 + (tid & 31);
      cstore1(&h0s[sl * H_DIM + r], (sl == 0) ? 4.f : 0.f);
    }
    start_barrier(bslots, wg, tid, runbase + 1);

    for (int s = 1; s <= L_SEQ; ++s) {
      const int P = s & 1;
      float4 xv;
      if (tid < 64) xv = ((const float4*)x)[(size_t)(s - 1) * 64 + tid];
      float4 hv = poll4(h0s + ((s - 1) & RM) * H_DIM + (tid << 2), tagc(s - 1));
      lds4[P][64 + tid] = hv;
      if (tid < 64) lds4[P][tid] = xv;
      if ((s & 3) == 0 && s >= 12 && tid < NWG1) {
        // throttle (every 4th step, overlapped): all L1 WGs >= s-11
        const float c = tagc(s - TLAG);
        const float* tp = h1s + ((s - TLAG) & RM) * H_DIM + (tid << 4);
        while (__builtin_fabsf(cload1(tp) - c) > 1.f) __builtin_amdgcn_s_sleep(1);
      }
      __syncthreads();
      float acc = 0.f;
      #pragma unroll
      for (int k = 0; k < 4; ++k) {
        float4 h = lds4[P][cg + 16 * k];
        acc += wihr[k].x * h.x + wihr[k].y * h.y + wihr[k].z * h.z + wihr[k].w * h.w;
      }
      #pragma unroll
      for (int k = 0; k < 32; ++k) {
        float4 h = lds4[P][64 + cg + 16 * k];
        acc += whhr[k].x * h.x + whhr[k].y * h.y + whhr[k].z * h.z + whhr[k].w * h.w;
      }
      acc += __shfl_xor(acc, 1);
      acc += __shfl_xor(acc, 2);
      acc += __shfl_xor(acc, 4);
      acc += __shfl_xor(acc, 8);
      // packed publish: one dwordx4 per wave (rows wv*4 .. wv*4+3)
      float hval = tanh_fast(acc + bias) + tagc(s);
      float g1 = __shfl(hval, 16);
      float g2 = __shfl(hval, 32);
      float g3 = __shfl(hval, 48);
      if ((tid & 63) == 0)
        cstore4f(h0s + (s & RM) * H_DIM + wg * 32 + wv * 4, hval, g1, g2, g3);
    }

    if (wg == 0) {
      // FC: sigmoid(h1_8192 . Wfc + bfc); slot 8192&15 = 0, ctr 4.
      // Last throttle (s=8192) gave L1 >= 8181 => slot 0 holds 8176 (tag 1,
      // rejected) or 8192 (tag 0, accepted).
      float4 hv = poll4(h1s + (tid << 2), tagc(L_SEQ));
      float4 wf = ((const float4*)Wfc)[tid];
      float pz = hv.x * wf.x + hv.y * wf.y + hv.z * wf.z + hv.w * wf.w;
      #pragma unroll
      for (int m = 1; m < 64; m <<= 1) pz += __shfl_xor(pz, m);
      float* red = (float*)&lds4[0][0];
      __syncthreads();
      if ((tid & 63) == 0) red[wv] = pz;
      __syncthreads();
      if (tid == 0) {
        float z = bfc[0];
        #pragma unroll
        for (int w = 0; w < 8; ++w) z += red[w];
        out[0] = 1.f / (1.f + __expf(-z));
        cstoreu(runctr, runbase + 1);
      }
    }
  } else {
    // -------- layer 1: 16 rows/WG, 32 threads/row, PARALLEL dual-poll --------
    const int cg  = tid & 31;
    const int wgl = wg - NWG0;
    const int row = wgl * 16 + (tid >> 5);
    float4 wihr[16], whhr[16];
    {
      const float* wr = Wih1 + (size_t)row * H_DIM + (cg << 2);
      #pragma unroll
      for (int k = 0; k < 16; ++k) wihr[k] = ld4(wr + (k << 7));
      const float* wr2 = Whh1 + (size_t)row * H_DIM + (cg << 2);
      #pragma unroll
      for (int k = 0; k < 16; ++k) whhr[k] = ld4(wr2 + (k << 7));
    }
    const float bias = bih1[row] + bhh1[row];

    if (tid < 256) {   // re-init all 16 ring slots of owned rows
      int sl = tid >> 4; int r = wgl * 16 + (tid & 15);
      cstore1(&h1s[sl * H_DIM + r], (sl == 0) ? 4.f : 0.f);
    }
    start_barrier(bslots, wg, tid, runbase + 1);

    for (int t = 1; t <= L_SEQ; ++t) {
      const int P = t & 1;
      // Concurrent polls: waves 0-3 fetch h0_t, waves 4-7 fetch h1_{t-1}.
      if (tid < 256) {
        float4 a, b;
        poll8(h0s + (t & RM) * H_DIM + (tid << 3), tagc(t), a, b);
        lds4[P][2 * tid] = a;
        lds4[P][2 * tid + 1] = b;
      } else {
        const int j = tid - 256;
        float4 a, b;
        poll8(h1s + ((t - 1) & RM) * H_DIM + (j << 3), tagc(t - 1), a, b);
        lds4[P][512 + 2 * j] = a;
        lds4[P][512 + 2 * j + 1] = b;
      }
      __syncthreads();
      float acc = 0.f;
      #pragma unroll
      for (int k = 0; k < 16; ++k) {
        float4 h = lds4[P][cg + 32 * k];
        acc += wihr[k].x * h.x + wihr[k].y * h.y + wihr[k].z * h.z + wihr[k].w * h.w;
      }
      #pragma unroll
      for (int k = 0; k < 16; ++k) {
        float4 h = lds4[P][512 + cg + 32 * k];
        acc += whhr[k].x * h.x + whhr[k].y * h.y + whhr[k].z * h.z + whhr[k].w * h.w;
      }
      acc += __shfl_xor(acc, 1);
      acc += __shfl_xor(acc, 2);
      acc += __shfl_xor(acc, 4);
      acc += __shfl_xor(acc, 8);
      acc += __shfl_xor(acc, 16);
      // packed publish: one dwordx2 per wave (rows wv*2, wv*2+1)
      float hval = tanh_fast(acc + bias) + tagc(t);
      float g1 = __shfl(hval, 32);
      if ((tid & 63) == 0)
        cstore2f(h1s + (t & RM) * H_DIM + wgl * 16 + wv * 2, hval, g1);
    }
  }
}

extern "C" void kernel_launch(void* const* d_in, const int* in_sizes, int n_in,
                              void* d_out, int out_size, void* d_ws, size_t ws_size,
                              hipStream_t stream) {
  const float* xx   = (const float*)d_in[0];
  const float* Wih0 = (const float*)d_in[1];
  const float* Whh0 = (const float*)d_in[2];
  const float* bih0 = (const float*)d_in[3];
  const float* bhh0 = (const float*)d_in[4];
  const float* Wih1 = (const float*)d_in[5];
  const float* Whh1 = (const float*)d_in[6];
  const float* bih1 = (const float*)d_in[7];
  const float* bhh1 = (const float*)d_in[8];
  const float* Wfc  = (const float*)d_in[9];
  const float* bfc  = (const float*)d_in[10];

  unsigned* runctr = (unsigned*)d_ws;
  unsigned* bslots = (unsigned*)((char*)d_ws + 256);
  float* h0s       = (float*)((char*)d_ws + 4096);
  float* h1s       = (float*)((char*)d_ws + 4096 + RD * H_DIM * sizeof(float));

  rnn2_dualpoll<<<dim3(NWG), dim3(TPB), 0, stream>>>(
      xx, Wih0, Whh0, bih0, bhh0, Wih1, Whh1, bih1, bhh1, Wfc, bfc,
      (float*)d_out, runctr, bslots, h0s, h1s);
}

// Round 14
// 29068.875 us; speedup vs baseline: 1.0097x; 1.0097x over previous
//
#include <hip/hip_runtime.h>
#include <math.h>

#define L_SEQ 8192
#define I_DIM 256
#define H_DIM 2048
#define NWG0  128         // layer-0: 128 WGs x 16 rows (32 thr/row)  [was 64x32]
#define NWG1  128         // layer-1: 128 WGs x 16 rows (32 thr/row)
#define NWG   (NWG0 + NWG1)
#define TPB   512
#define RD    16          // h ring depth
#define RM    (RD - 1)
#define TLAG  11          // L0 throttle lag (checked every 4th step)

// ws (bytes): [0] runctr | [1024..2048) bslots[256] | [4096) h0 ring 16*2048 f32
//             | [4096+128K) h1 ring 16*2048 f32
//
// Base = round-12 (best: 24.7 ms). Tagged dataflow: published value =
// h + ctr(step), ctr = 4+8*((step>>4)&1), ring 16, valid iff |v-ctr|<=1;
// per-run slot re-init (slot0 = tagged h_0, slots 1..15 = 0.0f invalid);
// 0xAA poison and 0.0f fail both windows. Start barrier on monotone runctr.
// Throttle lag 11 every 4th step (margins proven r12). Weight arrays
// float4[...] constant-unrolled (no-scratch codegen -- DO NOT restructure).
// L1 split-dot: poll h0_t + ih-dot FIRST, then poll h1_{t-1} late (laggard
// polled after ~900cy of work => first probe hits). r13's early dual-poll
// REGRESSED -- do not re-introduce.
//
// Round-14 diff: L0 mirrored to L1's geometry (128 WGs x 16 rows, 32 thr/row,
// 18 f4/thread). Halves L0's dot (~700->350 cy) so L0 builds its permitted
// 11-step lag => L1's h0 poll becomes a first-probe hit and L0's own cycle
// shrinks. Grid = 256 WGs: worst-case placement still leaves all WGs resident
// (VGPR<=128 allows 2 WG/CU), so the dataflow cannot deadlock.

typedef float f32x4 __attribute__((ext_vector_type(4)));
typedef float f32x2 __attribute__((ext_vector_type(2)));

__device__ __forceinline__ void cstore1(float* p, float v) {
  asm volatile("global_store_dword %0, %1, off sc0 sc1" :: "v"(p), "v"(v) : "memory");
}
__device__ __forceinline__ void cstore2f(float* p, float a, float b) {
  f32x2 v; v.x = a; v.y = b;
  asm volatile("global_store_dwordx2 %0, %1, off sc0 sc1" :: "v"(p), "v"(v) : "memory");
}
__device__ __forceinline__ void cstoreu(unsigned* p, unsigned v) {
  asm volatile("global_store_dword %0, %1, off sc0 sc1" :: "v"(p), "v"(v) : "memory");
}
__device__ __forceinline__ float cload1(const float* p) {
  float v;
  asm volatile("global_load_dword %0, %1, off sc0 sc1\n\ts_waitcnt vmcnt(0)"
               : "=v"(v) : "v"(p) : "memory");
  return v;
}
__device__ __forceinline__ unsigned cloadu(const unsigned* p) {
  unsigned v;
  asm volatile("global_load_dword %0, %1, off sc0 sc1\n\ts_waitcnt vmcnt(0)"
               : "=v"(v) : "v"(p) : "memory");
  return v;
}
__device__ __forceinline__ float4 cload4(const float* p) {
  float4 v;
  asm volatile("global_load_dwordx4 %0, %1, off sc0 sc1\n\ts_waitcnt vmcnt(0)"
               : "=v"(v) : "v"(p) : "memory");
  return v;
}
__device__ __forceinline__ float4 ld4(const float* p) {   // weight load, opaque
  float4 v;
  asm volatile("global_load_dwordx4 %0, %1, off\n\ts_waitcnt vmcnt(0)"
               : "=v"(v) : "v"(p) : "memory");
  return v;
}
__device__ __forceinline__ float tagc(int step) {
  return 4.f + 8.f * (float)((step >> 4) & 1);
}
__device__ __forceinline__ bool ok4(float4 v, float c) {
  return __builtin_fabsf(v.x - c) <= 1.f && __builtin_fabsf(v.y - c) <= 1.f &&
         __builtin_fabsf(v.z - c) <= 1.f && __builtin_fabsf(v.w - c) <= 1.f;
}
__device__ __forceinline__ float4 poll4(const float* p, float c) {
  float4 v = cload4(p);
  while (!ok4(v, c)) { __builtin_amdgcn_s_sleep(1); v = cload4(p); }
  return make_float4(v.x - c, v.y - c, v.z - c, v.w - c);
}
__device__ __forceinline__ float tanh_fast(float v) {   // exact identity
  float e = __expf(2.f * v);
  return 1.f - 2.f / (e + 1.f);
}
__device__ __forceinline__ void start_barrier(unsigned* bslots, int wg, int tid, unsigned value) {
  __syncthreads();
  if (tid == 0) cstoreu(&bslots[wg], value);
  if (tid < NWG) {
    while ((int)(cloadu(&bslots[tid]) - value) < 0) __builtin_amdgcn_s_sleep(1);
  }
  __syncthreads();
}

__global__ __launch_bounds__(TPB, 2)
void rnn2_l0split(const float* __restrict__ x,
                  const float* __restrict__ Wih0, const float* __restrict__ Whh0,
                  const float* __restrict__ bih0, const float* __restrict__ bhh0,
                  const float* __restrict__ Wih1, const float* __restrict__ Whh1,
                  const float* __restrict__ bih1, const float* __restrict__ bhh1,
                  const float* __restrict__ Wfc,  const float* __restrict__ bfc,
                  float* __restrict__ out,
                  unsigned* __restrict__ runctr, unsigned* __restrict__ bslots,
                  float* __restrict__ h0s, float* __restrict__ h1s)
{
  const int wg  = blockIdx.x;
  const int tid = threadIdx.x;
  const int wv  = tid >> 6;
  __shared__ float4 lds4[2][1024];

  const unsigned runbase = cloadu(runctr);

  if (wg < NWG0) {
    // ------------ layer 0: 16 rows/WG, 32 thr/row (mirrors L1 geometry) ------------
    const int cg  = tid & 31;
    const int row = wg * 16 + (tid >> 5);
    float4 wihr[2], whhr[16];
    {
      const float* wr = Wih0 + (size_t)row * I_DIM + (cg << 2);
      #pragma unroll
      for (int k = 0; k < 2; ++k) wihr[k] = ld4(wr + (k << 7));
      const float* wr2 = Whh0 + (size_t)row * H_DIM + (cg << 2);
      #pragma unroll
      for (int k = 0; k < 16; ++k) whhr[k] = ld4(wr2 + (k << 7));
    }
    const float bias = bih0[row] + bhh0[row];

    if (tid < 256) {   // re-init all 16 ring slots of owned rows (16/slot)
      int sl = tid >> 4; int r = wg * 16 + (tid & 15);
      cstore1(&h0s[sl * H_DIM + r], (sl == 0) ? 4.f : 0.f);
    }
    start_barrier(bslots, wg, tid, runbase + 1);

    for (int s = 1; s <= L_SEQ; ++s) {
      const int P = s & 1;
      float4 xv;
      if (tid < 64) xv = ((const float4*)x)[(size_t)(s - 1) * 64 + tid];
      float4 hv = poll4(h0s + ((s - 1) & RM) * H_DIM + (tid << 2), tagc(s - 1));
      lds4[P][64 + tid] = hv;
      if (tid < 64) lds4[P][tid] = xv;
      if ((s & 3) == 0 && s >= 12 && tid < NWG1) {
        // throttle (every 4th step, overlapped): all L1 WGs >= s-11
        const float c = tagc(s - TLAG);
        const float* tp = h1s + ((s - TLAG) & RM) * H_DIM + (tid << 4);
        while (__builtin_fabsf(cload1(tp) - c) > 1.f) __builtin_amdgcn_s_sleep(1);
      }
      __syncthreads();
      float acc = 0.f;
      #pragma unroll
      for (int k = 0; k < 2; ++k) {      // x part: f4 idx cg + 32k in [0,64)
        float4 h = lds4[P][cg + 32 * k];
        acc += wihr[k].x * h.x + wihr[k].y * h.y + wihr[k].z * h.z + wihr[k].w * h.w;
      }
      #pragma unroll
      for (int k = 0; k < 16; ++k) {     // h part: f4 idx 64 + cg + 32k
        float4 h = lds4[P][64 + cg + 32 * k];
        acc += whhr[k].x * h.x + whhr[k].y * h.y + whhr[k].z * h.z + whhr[k].w * h.w;
      }
      acc += __shfl_xor(acc, 1);
      acc += __shfl_xor(acc, 2);
      acc += __shfl_xor(acc, 4);
      acc += __shfl_xor(acc, 8);
      acc += __shfl_xor(acc, 16);
      // packed publish: one dwordx2 per wave (rows wv*2, wv*2+1)
      float hval = tanh_fast(acc + bias) + tagc(s);
      float g1 = __shfl(hval, 32);
      if ((tid & 63) == 0)
        cstore2f(h0s + (s & RM) * H_DIM + wg * 16 + wv * 2, hval, g1);
    }

    if (wg == 0) {
      // FC: sigmoid(h1_8192 . Wfc + bfc); slot 8192&15 = 0, ctr 4.
      // Last throttle (s=8192) gave L1 >= 8181 => slot 0 holds 8176 (tag 1,
      // rejected) or 8192 (tag 0, accepted).
      float4 hv = poll4(h1s + (tid << 2), tagc(L_SEQ));
      float4 wf = ((const float4*)Wfc)[tid];
      float pz = hv.x * wf.x + hv.y * wf.y + hv.z * wf.z + hv.w * wf.w;
      #pragma unroll
      for (int m = 1; m < 64; m <<= 1) pz += __shfl_xor(pz, m);
      float* red = (float*)&lds4[0][0];
      __syncthreads();
      if ((tid & 63) == 0) red[wv] = pz;
      __syncthreads();
      if (tid == 0) {
        float z = bfc[0];
        #pragma unroll
        for (int w = 0; w < 8; ++w) z += red[w];
        out[0] = 1.f / (1.f + __expf(-z));
        cstoreu(runctr, runbase + 1);
      }
    }
  } else {
    // -------- layer 1: 16 rows/WG, 32 thr/row, split-dot (= round 12) --------
    const int cg  = tid & 31;
    const int wgl = wg - NWG0;
    const int row = wgl * 16 + (tid >> 5);
    float4 wihr[16], whhr[16];
    {
      const float* wr = Wih1 + (size_t)row * H_DIM + (cg << 2);
      #pragma unroll
      for (int k = 0; k < 16; ++k) wihr[k] = ld4(wr + (k << 7));
      const float* wr2 = Whh1 + (size_t)row * H_DIM + (cg << 2);
      #pragma unroll
      for (int k = 0; k < 16; ++k) whhr[k] = ld4(wr2 + (k << 7));
    }
    const float bias = bih1[row] + bhh1[row];

    if (tid < 256) {   // re-init all 16 ring slots of owned rows
      int sl = tid >> 4; int r = wgl * 16 + (tid & 15);
      cstore1(&h1s[sl * H_DIM + r], (sl == 0) ? 4.f : 0.f);
    }
    start_barrier(bslots, wg, tid, runbase + 1);

    for (int t = 1; t <= L_SEQ; ++t) {
      const int P = t & 1;
      // phase A: h0_t (L0 runs up to 11 ahead -- first-probe hit)
      float4 a = poll4(h0s + (t & RM) * H_DIM + (tid << 2), tagc(t));
      lds4[P][tid] = a;
      __syncthreads();
      float acc = 0.f;
      #pragma unroll
      for (int k = 0; k < 16; ++k) {
        float4 h = lds4[P][cg + 32 * k];
        acc += wihr[k].x * h.x + wihr[k].y * h.y + wihr[k].z * h.z + wihr[k].w * h.w;
      }
      // phase B: h1_{t-1} -- the critical detect, polled late.
      float4 b = poll4(h1s + ((t - 1) & RM) * H_DIM + (tid << 2), tagc(t - 1));
      lds4[P][512 + tid] = b;
      __syncthreads();
      #pragma unroll
      for (int k = 0; k < 16; ++k) {
        float4 h = lds4[P][512 + cg + 32 * k];
        acc += whhr[k].x * h.x + whhr[k].y * h.y + whhr[k].z * h.z + whhr[k].w * h.w;
      }
      acc += __shfl_xor(acc, 1);
      acc += __shfl_xor(acc, 2);
      acc += __shfl_xor(acc, 4);
      acc += __shfl_xor(acc, 8);
      acc += __shfl_xor(acc, 16);
      // packed publish: one dwordx2 per wave (rows wv*2, wv*2+1)
      float hval = tanh_fast(acc + bias) + tagc(t);
      float g1 = __shfl(hval, 32);
      if ((tid & 63) == 0)
        cstore2f(h1s + (t & RM) * H_DIM + wgl * 16 + wv * 2, hval, g1);
    }
  }
}

extern "C" void kernel_launch(void* const* d_in, const int* in_sizes, int n_in,
                              void* d_out, int out_size, void* d_ws, size_t ws_size,
                              hipStream_t stream) {
  const float* xx   = (const float*)d_in[0];
  const float* Wih0 = (const float*)d_in[1];
  const float* Whh0 = (const float*)d_in[2];
  const float* bih0 = (const float*)d_in[3];
  const float* bhh0 = (const float*)d_in[4];
  const float* Wih1 = (const float*)d_in[5];
  const float* Whh1 = (const float*)d_in[6];
  const float* bih1 = (const float*)d_in[7];
  const float* bhh1 = (const float*)d_in[8];
  const float* Wfc  = (const float*)d_in[9];
  const float* bfc  = (const float*)d_in[10];

  unsigned* runctr = (unsigned*)d_ws;
  unsigned* bslots = (unsigned*)((char*)d_ws + 1024);   // 256 entries
  float* h0s       = (float*)((char*)d_ws + 4096);
  float* h1s       = (float*)((char*)d_ws + 4096 + RD * H_DIM * sizeof(float));

  rnn2_l0split<<<dim3(NWG), dim3(TPB), 0, stream>>>(
      xx, Wih0, Whh0, bih0, bhh0, Wih1, Whh1, bih1, bhh1, Wfc, bfc,
      (float*)d_out, runctr, bslots, h0s, h1s);
}

// Round 15
// 23233.807 us; speedup vs baseline: 1.2633x; 1.2511x over previous
//
#include <hip/hip_runtime.h>
#include <math.h>

#define L_SEQ 8192
#define I_DIM 256
#define H_DIM 2048
#define NWG0  64          // layer-0: 64 WGs x 32 rows (16 thr/row)
#define NWG1  128         // layer-1: 128 WGs x 16 rows (32 thr/row)
#define NWG   (NWG0 + NWG1)
#define TPB   512
#define RD    16          // h ring depth
#define RM    (RD - 1)
#define TLAG  11          // L0 throttle lag (checked every 4th step)

// ws (bytes): [0] runctr | [256..1024) bslots | [4096) h0 ring 16*2048 f32
//             | [4096+128K) h1 ring 16*2048 f32
//
// Base = round-12 (best: 24.7 ms) EXACTLY: geometry 64/128, tagged dataflow
// (value = h + ctr(step), ctr = 4+8*((step>>4)&1), ring 16, |v-ctr|<=1 valid),
// per-run slot re-init, start barrier on monotone runctr, throttle lag 11
// every 4th step, packed publishes, s_sleep backoff, L1 split-dot with the
// h1 poll in its proven-late position. Weight arrays constant-unrolled
// (no-scratch codegen -- DO NOT restructure). r13 (early h1 poll) and r14
// (more L0 WGs) both REGRESSED -- do not re-introduce.
//
// Round-15 diffs:
//  1. L1 h0-PREFETCH (issue-early/wait-late): pf(h0_{t+1}) issued right after
//     staging h0_t; the h1 poll's embedded vmcnt(0) later in the SAME iter
//     physically drains it, so next iter's pf-wait is vmcnt(1) (leaves the
//     recent publish store outstanding) + register tie -> ~free. Removes
//     RT_h0 (~0.6us) from L1's serial path. Tag check + poll fallback keeps
//     correctness if L0 hasn't published h0_{t+1} yet.
//  2. L0 x-trim: x-partial for step s+1 computed AFTER publishing h0_s from
//     plain cached loads (no LDS staging) -> x work off the detect->publish
//     path.

typedef float f32x4 __attribute__((ext_vector_type(4)));
typedef float f32x2 __attribute__((ext_vector_type(2)));

__device__ __forceinline__ void cstore1(float* p, float v) {
  asm volatile("global_store_dword %0, %1, off sc0 sc1" :: "v"(p), "v"(v) : "memory");
}
__device__ __forceinline__ void cstore2f(float* p, float a, float b) {
  f32x2 v; v.x = a; v.y = b;
  asm volatile("global_store_dwordx2 %0, %1, off sc0 sc1" :: "v"(p), "v"(v) : "memory");
}
__device__ __forceinline__ void cstore4f(float* p, float a, float b, float c, float d) {
  f32x4 v; v.x = a; v.y = b; v.z = c; v.w = d;
  asm volatile("global_store_dwordx4 %0, %1, off sc0 sc1" :: "v"(p), "v"(v) : "memory");
}
__device__ __forceinline__ void cstoreu(unsigned* p, unsigned v) {
  asm volatile("global_store_dword %0, %1, off sc0 sc1" :: "v"(p), "v"(v) : "memory");
}
__device__ __forceinline__ float cload1(const float* p) {
  float v;
  asm volatile("global_load_dword %0, %1, off sc0 sc1\n\ts_waitcnt vmcnt(0)"
               : "=v"(v) : "v"(p) : "memory");
  return v;
}
__device__ __forceinline__ unsigned cloadu(const unsigned* p) {
  unsigned v;
  asm volatile("global_load_dword %0, %1, off sc0 sc1\n\ts_waitcnt vmcnt(0)"
               : "=v"(v) : "v"(p) : "memory");
  return v;
}
__device__ __forceinline__ float4 cload4(const float* p) {
  float4 v;
  asm volatile("global_load_dwordx4 %0, %1, off sc0 sc1\n\ts_waitcnt vmcnt(0)"
               : "=v"(v) : "v"(p) : "memory");
  return v;
}
__device__ __forceinline__ float4 ld4(const float* p) {   // weight load, opaque
  float4 v;
  asm volatile("global_load_dwordx4 %0, %1, off\n\ts_waitcnt vmcnt(0)"
               : "=v"(v) : "v"(p) : "memory");
  return v;
}
// prefetch: issue WITHOUT waitcnt; completion provided by a later vmcnt(0)
__device__ __forceinline__ void pf_issue(f32x4& v, const float* p) {
  asm volatile("global_load_dwordx4 %0, %1, off sc0 sc1" : "=&v"(v) : "v"(p) : "memory");
}
// wait: vmcnt(1) lets the recent publish store stay outstanding; pf itself was
// drained by the previous iteration's poll4 vmcnt(0) (or the prologue drain).
__device__ __forceinline__ void pf_wait(f32x4& v) {
  asm volatile("s_waitcnt vmcnt(1)" : "+v"(v) :: "memory");
  __builtin_amdgcn_sched_barrier(0);
}
__device__ __forceinline__ float tagc(int step) {
  return 4.f + 8.f * (float)((step >> 4) & 1);
}
__device__ __forceinline__ bool ok4(float4 v, float c) {
  return __builtin_fabsf(v.x - c) <= 1.f && __builtin_fabsf(v.y - c) <= 1.f &&
         __builtin_fabsf(v.z - c) <= 1.f && __builtin_fabsf(v.w - c) <= 1.f;
}
__device__ __forceinline__ bool ok4x(f32x4 v, float c) {
  return __builtin_fabsf(v.x - c) <= 1.f && __builtin_fabsf(v.y - c) <= 1.f &&
         __builtin_fabsf(v.z - c) <= 1.f && __builtin_fabsf(v.w - c) <= 1.f;
}
__device__ __forceinline__ float4 poll4(const float* p, float c) {
  float4 v = cload4(p);
  while (!ok4(v, c)) { __builtin_amdgcn_s_sleep(1); v = cload4(p); }
  return make_float4(v.x - c, v.y - c, v.z - c, v.w - c);
}
__device__ __forceinline__ float tanh_fast(float v) {   // exact identity
  float e = __expf(2.f * v);
  return 1.f - 2.f / (e + 1.f);
}
__device__ __forceinline__ void start_barrier(unsigned* bslots, int wg, int tid, unsigned value) {
  __syncthreads();
  if (tid == 0) cstoreu(&bslots[wg], value);
  if (tid < NWG) {
    while ((int)(cloadu(&bslots[tid]) - value) < 0) __builtin_amdgcn_s_sleep(1);
  }
  __syncthreads();
}

__global__ __launch_bounds__(TPB, 2)
void rnn2_pfetch(const float* __restrict__ x,
                 const float* __restrict__ Wih0, const float* __restrict__ Whh0,
                 const float* __restrict__ bih0, const float* __restrict__ bhh0,
                 const float* __restrict__ Wih1, const float* __restrict__ Whh1,
                 const float* __restrict__ bih1, const float* __restrict__ bhh1,
                 const float* __restrict__ Wfc,  const float* __restrict__ bfc,
                 float* __restrict__ out,
                 unsigned* __restrict__ runctr, unsigned* __restrict__ bslots,
                 float* __restrict__ h0s, float* __restrict__ h1s)
{
  const int wg  = blockIdx.x;
  const int tid = threadIdx.x;
  const int wv  = tid >> 6;
  __shared__ float4 lds4[2][1024];

  const unsigned runbase = cloadu(runctr);

  if (wg < NWG0) {
    // ---------------- layer 0: 32 rows/WG, 16 threads/row ----------------
    const int cg  = tid & 15;
    const int row = wg * 32 + (tid >> 4);
    float4 wihr[4], whhr[32];
    {
      const float* wr = Wih0 + (size_t)row * I_DIM + (cg << 2);
      #pragma unroll
      for (int k = 0; k < 4; ++k) wihr[k] = ld4(wr + (k << 6));
      const float* wr2 = Whh0 + (size_t)row * H_DIM + (cg << 2);
      #pragma unroll
      for (int k = 0; k < 32; ++k) whhr[k] = ld4(wr2 + (k << 6));
    }
    const float bias = bih0[row] + bhh0[row];

    {   // re-init all 16 ring slots of owned rows: slot0 = tagged h0_0 (=4.0)
      int sl = tid >> 5; int r = wg * 32 + (tid & 31);
      cstore1(&h0s[sl * H_DIM + r], (sl == 0) ? 4.f : 0.f);
    }
    start_barrier(bslots, wg, tid, runbase + 1);

    // x-partial for s=1 (plain cached loads; columns cg*4 + k*64)
    float xpart = 0.f;
    #pragma unroll
    for (int k = 0; k < 4; ++k) {
      float4 xv = ((const float4*)x)[cg + 16 * k];
      xpart += wihr[k].x * xv.x + wihr[k].y * xv.y + wihr[k].z * xv.z + wihr[k].w * xv.w;
    }

    for (int s = 1; s <= L_SEQ; ++s) {
      const int P = s & 1;
      float4 hv = poll4(h0s + ((s - 1) & RM) * H_DIM + (tid << 2), tagc(s - 1));
      lds4[P][tid] = hv;
      if ((s & 3) == 0 && s >= 12 && tid < NWG1) {
        // throttle (every 4th step, overlapped): all L1 WGs >= s-11
        const float c = tagc(s - TLAG);
        const float* tp = h1s + ((s - TLAG) & RM) * H_DIM + (tid << 4);
        while (__builtin_fabsf(cload1(tp) - c) > 1.f) __builtin_amdgcn_s_sleep(1);
      }
      __syncthreads();
      float acc = xpart;
      #pragma unroll
      for (int k = 0; k < 32; ++k) {
        float4 h = lds4[P][cg + 16 * k];
        acc += whhr[k].x * h.x + whhr[k].y * h.y + whhr[k].z * h.z + whhr[k].w * h.w;
      }
      acc += __shfl_xor(acc, 1);
      acc += __shfl_xor(acc, 2);
      acc += __shfl_xor(acc, 4);
      acc += __shfl_xor(acc, 8);
      // packed publish: one dwordx4 per wave (rows wv*4 .. wv*4+3)
      float hval = tanh_fast(acc + bias) + tagc(s);
      float g1 = __shfl(hval, 16);
      float g2 = __shfl(hval, 32);
      float g3 = __shfl(hval, 48);
      if ((tid & 63) == 0)
        cstore4f(h0s + (s & RM) * H_DIM + wg * 32 + wv * 4, hval, g1, g2, g3);
      // x-partial for step s+1, off the detect->publish path
      if (s < L_SEQ) {
        xpart = 0.f;
        #pragma unroll
        for (int k = 0; k < 4; ++k) {
          float4 xv = ((const float4*)x)[s * 64 + cg + 16 * k];
          xpart += wihr[k].x * xv.x + wihr[k].y * xv.y + wihr[k].z * xv.z + wihr[k].w * xv.w;
        }
      }
    }

    if (wg == 0) {
      // FC: sigmoid(h1_8192 . Wfc + bfc); slot 8192&15 = 0, ctr 4.
      // Last throttle (s=8192) gave L1 >= 8181 => slot 0 holds 8176 (tag 1,
      // rejected) or 8192 (tag 0, accepted).
      float4 hv = poll4(h1s + (tid << 2), tagc(L_SEQ));
      float4 wf = ((const float4*)Wfc)[tid];
      float pz = hv.x * wf.x + hv.y * wf.y + hv.z * wf.z + hv.w * wf.w;
      #pragma unroll
      for (int m = 1; m < 64; m <<= 1) pz += __shfl_xor(pz, m);
      float* red = (float*)&lds4[0][0];
      __syncthreads();
      if ((tid & 63) == 0) red[wv] = pz;
      __syncthreads();
      if (tid == 0) {
        float z = bfc[0];
        #pragma unroll
        for (int w = 0; w < 8; ++w) z += red[w];
        out[0] = 1.f / (1.f + __expf(-z));
        cstoreu(runctr, runbase + 1);
      }
    }
  } else {
    // -------- layer 1: 16 rows/WG, 32 thr/row, split-dot + h0 prefetch --------
    const int cg  = tid & 31;
    const int wgl = wg - NWG0;
    const int row = wgl * 16 + (tid >> 5);
    float4 wihr[16], whhr[16];
    {
      const float* wr = Wih1 + (size_t)row * H_DIM + (cg << 2);
      #pragma unroll
      for (int k = 0; k < 16; ++k) wihr[k] = ld4(wr + (k << 7));
      const float* wr2 = Whh1 + (size_t)row * H_DIM + (cg << 2);
      #pragma unroll
      for (int k = 0; k < 16; ++k) whhr[k] = ld4(wr2 + (k << 7));
    }
    const float bias = bih1[row] + bhh1[row];

    if (tid < 256) {   // re-init all 16 ring slots of owned rows
      int sl = tid >> 4; int r = wgl * 16 + (tid & 15);
      cstore1(&h1s[sl * H_DIM + r], (sl == 0) ? 4.f : 0.f);
    }
    start_barrier(bslots, wg, tid, runbase + 1);

    // prologue: issue prefetch of h0_1, then force a drain so pf is complete
    f32x4 pf;
    pf_issue(pf, h0s + (1 & RM) * H_DIM + (tid << 2));
    (void)cloadu(runctr);   // embedded vmcnt(0) drains pf

    for (int t = 1; t <= L_SEQ; ++t) {
      const int P = t & 1;
      const float c0 = tagc(t);
      // phase A: h0_t from prefetch (validated; poll fallback if L0 not there yet)
      pf_wait(pf);
      if (!ok4x(pf, c0)) {
        const float* p0 = h0s + (t & RM) * H_DIM + (tid << 2);
        do {
          __builtin_amdgcn_s_sleep(1);
          float4 r = cload4(p0);
          pf.x = r.x; pf.y = r.y; pf.z = r.z; pf.w = r.w;
        } while (!ok4x(pf, c0));
      }
      lds4[P][tid] = make_float4(pf.x - c0, pf.y - c0, pf.z - c0, pf.w - c0);
      if (t < L_SEQ)   // issue next prefetch; drained by this iter's h1 poll
        pf_issue(pf, h0s + ((t + 1) & RM) * H_DIM + (tid << 2));
      __syncthreads();
      float acc = 0.f;
      #pragma unroll
      for (int k = 0; k < 16; ++k) {
        float4 h = lds4[P][cg + 32 * k];
        acc += wihr[k].x * h.x + wihr[k].y * h.y + wihr[k].z * h.z + wihr[k].w * h.w;
      }
      // phase B: h1_{t-1} -- the critical detect, polled late (proven position)
      float4 b = poll4(h1s + ((t - 1) & RM) * H_DIM + (tid << 2), tagc(t - 1));
      lds4[P][512 + tid] = b;
      __syncthreads();
      #pragma unroll
      for (int k = 0; k < 16; ++k) {
        float4 h = lds4[P][512 + cg + 32 * k];
        acc += whhr[k].x * h.x + whhr[k].y * h.y + whhr[k].z * h.z + whhr[k].w * h.w;
      }
      acc += __shfl_xor(acc, 1);
      acc += __shfl_xor(acc, 2);
      acc += __shfl_xor(acc, 4);
      acc += __shfl_xor(acc, 8);
      acc += __shfl_xor(acc, 16);
      // packed publish: one dwordx2 per wave (rows wv*2, wv*2+1)
      float hval = tanh_fast(acc + bias) + tagc(t);
      float g1 = __shfl(hval, 32);
      if ((tid & 63) == 0)
        cstore2f(h1s + (t & RM) * H_DIM + wgl * 16 + wv * 2, hval, g1);
    }
  }
}

extern "C" void kernel_launch(void* const* d_in, const int* in_sizes, int n_in,
                              void* d_out, int out_size, void* d_ws, size_t ws_size,
                              hipStream_t stream) {
  const float* xx   = (const float*)d_in[0];
  const float* Wih0 = (const float*)d_in[1];
  const float* Whh0 = (const float*)d_in[2];
  const float* bih0 = (const float*)d_in[3];
  const float* bhh0 = (const float*)d_in[4];
  const float* Wih1 = (const float*)d_in[5];
  const float* Whh1 = (const float*)d_in[6];
  const float* bih1 = (const float*)d_in[7];
  const float* bhh1 = (const float*)d_in[8];
  const float* Wfc  = (const float*)d_in[9];
  const float* bfc  = (const float*)d_in[10];

  unsigned* runctr = (unsigned*)d_ws;
  unsigned* bslots = (unsigned*)((char*)d_ws + 256);
  float* h0s       = (float*)((char*)d_ws + 4096);
  float* h1s       = (float*)((char*)d_ws + 4096 + RD * H_DIM * sizeof(float));

  rnn2_pfetch<<<dim3(NWG), dim3(TPB), 0, stream>>>(
      xx, Wih0, Whh0, bih0, bhh0, Wih1, Whh1, bih1, bhh1, Wfc, bfc,
      (float*)d_out, runctr, bslots, h0s, h1s);
}

// Round 17
// 18946.698 us; speedup vs baseline: 1.5491x; 1.2263x over previous
//
#include <hip/hip_runtime.h>
#include <math.h>

#define L_SEQ 8192
#define I_DIM 256
#define H_DIM 2048
#define NWG0  64          // layer-0: 64 WGs x 32 rows (col-block: 4 rows/wave)
#define NWG1  128         // layer-1: 128 WGs x 16 rows (col-block: 2 rows/wave)
#define NWG   (NWG0 + NWG1)
#define TPB   512
#define RD    16          // h ring depth
#define RM    (RD - 1)
#define TLAG  11          // L0 throttle lag (checked every 4th step)

// ws (bytes): [0] runctr | [256..1024) bslots | [4096) h0 ring 16*2048 f32
//             | [4096+128K) h1 ring 16*2048 f32
//
// Base = round-15 (best: 23.2 ms): tagged dataflow (value = h + ctr(step),
// ctr = 4+8*((step>>4)&1), ring 16, |v-ctr|<=1 valid), per-run slot re-init,
// start barrier on monotone runctr, throttle lag 11 every 4th step, packed
// publishes, s_sleep backoff, L1 h0-prefetch (issue-early/validate-late),
// L0 x-trim, L1 split-dot with late h1 poll. r13 (early h1 poll), r14 (128
// L0 WGs), r16 (staggered half-poll -- CRASHED) are all excluded.
//
// Round-17 diff: COLUMN-BLOCK compute in both layers (retry of r7's idea on
// the healthy base). Wave wv owns 4 rows (L0) / 2 rows (L1); lane l owns cols
// [32l,32l+32) = 8 float4 and reads ONLY those from LDS (padded pos j+(j>>3),
// 2-way conflicts = free per m136). Row sums via 6-level shfl_xor; lane 0
// ends up holding all its wave's row values -> packed publish with no gather
// shfls. LDS read traffic per WG-step: L0 256->64 KB, L1 256->128 KB.
// Weight arrays stay constant-unrolled float4 arrays (proven AGPR codegen).

typedef float f32x4 __attribute__((ext_vector_type(4)));
typedef float f32x2 __attribute__((ext_vector_type(2)));

__device__ __forceinline__ void cstore1(float* p, float v) {
  asm volatile("global_store_dword %0, %1, off sc0 sc1" :: "v"(p), "v"(v) : "memory");
}
__device__ __forceinline__ void cstore2f(float* p, float a, float b) {
  f32x2 v; v.x = a; v.y = b;
  asm volatile("global_store_dwordx2 %0, %1, off sc0 sc1" :: "v"(p), "v"(v) : "memory");
}
__device__ __forceinline__ void cstore4f(float* p, float a, float b, float c, float d) {
  f32x4 v; v.x = a; v.y = b; v.z = c; v.w = d;
  asm volatile("global_store_dwordx4 %0, %1, off sc0 sc1" :: "v"(p), "v"(v) : "memory");
}
__device__ __forceinline__ void cstoreu(unsigned* p, unsigned v) {
  asm volatile("global_store_dword %0, %1, off sc0 sc1" :: "v"(p), "v"(v) : "memory");
}
__device__ __forceinline__ float cload1(const float* p) {
  float v;
  asm volatile("global_load_dword %0, %1, off sc0 sc1\n\ts_waitcnt vmcnt(0)"
               : "=v"(v) : "v"(p) : "memory");
  return v;
}
__device__ __forceinline__ unsigned cloadu(const unsigned* p) {
  unsigned v;
  asm volatile("global_load_dword %0, %1, off sc0 sc1\n\ts_waitcnt vmcnt(0)"
               : "=v"(v) : "v"(p) : "memory");
  return v;
}
__device__ __forceinline__ float4 cload4(const float* p) {
  float4 v;
  asm volatile("global_load_dwordx4 %0, %1, off sc0 sc1\n\ts_waitcnt vmcnt(0)"
               : "=v"(v) : "v"(p) : "memory");
  return v;
}
__device__ __forceinline__ float4 ld4(const float* p) {   // weight load, opaque
  float4 v;
  asm volatile("global_load_dwordx4 %0, %1, off\n\ts_waitcnt vmcnt(0)"
               : "=v"(v) : "v"(p) : "memory");
  return v;
}
// prefetch: issue WITHOUT waitcnt; drained by a later vmcnt(0)
__device__ __forceinline__ void pf_issue(f32x4& v, const float* p) {
  asm volatile("global_load_dwordx4 %0, %1, off sc0 sc1" : "=&v"(v) : "v"(p) : "memory");
}
// wait: vmcnt(1) lets the recent publish store stay outstanding; the pf itself
// was drained by the previous iteration's poll4 vmcnt(0) (or prologue drain).
__device__ __forceinline__ void pf_wait1(f32x4& v) {
  asm volatile("s_waitcnt vmcnt(1)" : "+v"(v) :: "memory");
  __builtin_amdgcn_sched_barrier(0);
}
__device__ __forceinline__ float tagc(int step) {
  return 4.f + 8.f * (float)((step >> 4) & 1);
}
__device__ __forceinline__ bool ok4(float4 v, float c) {
  return __builtin_fabsf(v.x - c) <= 1.f && __builtin_fabsf(v.y - c) <= 1.f &&
         __builtin_fabsf(v.z - c) <= 1.f && __builtin_fabsf(v.w - c) <= 1.f;
}
__device__ __forceinline__ bool ok4x(f32x4 v, float c) {
  return __builtin_fabsf(v.x - c) <= 1.f && __builtin_fabsf(v.y - c) <= 1.f &&
         __builtin_fabsf(v.z - c) <= 1.f && __builtin_fabsf(v.w - c) <= 1.f;
}
__device__ __forceinline__ float4 poll4(const float* p, float c) {
  float4 v = cload4(p);
  while (!ok4(v, c)) { __builtin_amdgcn_s_sleep(1); v = cload4(p); }
  return make_float4(v.x - c, v.y - c, v.z - c, v.w - c);
}
// validate a prefetched granule; fall back to backoff-poll if stale
__device__ __forceinline__ float4 pf_finish(f32x4 pf, const float* p, float c) {
  if (!ok4x(pf, c)) {
    do {
      __builtin_amdgcn_s_sleep(1);
      float4 r = cload4(p);
      pf.x = r.x; pf.y = r.y; pf.z = r.z; pf.w = r.w;
    } while (!ok4x(pf, c));
  }
  return make_float4(pf.x - c, pf.y - c, pf.z - c, pf.w - c);
}
__device__ __forceinline__ float dot4(float4 a, float4 b) {
  return a.x * b.x + a.y * b.y + a.z * b.z + a.w * b.w;
}
__device__ __forceinline__ float tanh_fast(float v) {   // exact identity
  float e = __expf(2.f * v);
  return 1.f - 2.f / (e + 1.f);
}
__device__ __forceinline__ void start_barrier(unsigned* bslots, int wg, int tid, unsigned value) {
  __syncthreads();
  if (tid == 0) cstoreu(&bslots[wg], value);
  if (tid < NWG) {
    while ((int)(cloadu(&bslots[tid]) - value) < 0) __builtin_amdgcn_s_sleep(1);
  }
  __syncthreads();
}

__global__ __launch_bounds__(TPB, 2)
void rnn2_colb(const float* __restrict__ x,
               const float* __restrict__ Wih0, const float* __restrict__ Whh0,
               const float* __restrict__ bih0, const float* __restrict__ bhh0,
               const float* __restrict__ Wih1, const float* __restrict__ Whh1,
               const float* __restrict__ bih1, const float* __restrict__ bhh1,
               const float* __restrict__ Wfc,  const float* __restrict__ bfc,
               float* __restrict__ out,
               unsigned* __restrict__ runctr, unsigned* __restrict__ bslots,
               float* __restrict__ h0s, float* __restrict__ h1s)
{
  const int wg   = blockIdx.x;
  const int tid  = threadIdx.x;
  const int lane = tid & 63;
  const int wv   = tid >> 6;
  __shared__ float4 lds4[2][1152];   // padded: [0..576) h0, [576..1152) h1

  const unsigned runbase = cloadu(runctr);

  if (wg < NWG0) {
    // ---- layer 0: wave wv owns rows r0..r0+3; lane owns cols [32l, 32l+32) ----
    const int r0 = wg * 32 + wv * 4;
    float4 whhr[32];   // [j*8+k]: row r0+j, col f4 k of the lane's 8
    float4 wihr[4];    // [j]: row r0+j, x cols [4l, 4l+4)
    {
      #pragma unroll
      for (int j = 0; j < 4; ++j) {
        const float* wr2 = Whh0 + (size_t)(r0 + j) * H_DIM + (lane << 5);
        #pragma unroll
        for (int k = 0; k < 8; ++k) whhr[j * 8 + k] = ld4(wr2 + (k << 2));
        wihr[j] = ld4(Wih0 + (size_t)(r0 + j) * I_DIM + (lane << 2));
      }
    }
    const float bs0 = bih0[r0] + bhh0[r0];
    const float bs1 = bih0[r0 + 1] + bhh0[r0 + 1];
    const float bs2 = bih0[r0 + 2] + bhh0[r0 + 2];
    const float bs3 = bih0[r0 + 3] + bhh0[r0 + 3];

    {   // re-init all 16 ring slots of owned rows: slot0 = tagged h0_0 (=4.0)
      int sl = tid >> 5; int r = wg * 32 + (tid & 31);
      cstore1(&h0s[sl * H_DIM + r], (sl == 0) ? 4.f : 0.f);
    }
    start_barrier(bslots, wg, tid, runbase + 1);

    // x-partials for s=1 (row 0 of x; lane's 4 cols)
    float xp0, xp1, xp2, xp3;
    {
      float4 xv = ((const float4*)x)[lane];
      xp0 = dot4(wihr[0], xv); xp1 = dot4(wihr[1], xv);
      xp2 = dot4(wihr[2], xv); xp3 = dot4(wihr[3], xv);
    }

    for (int s = 1; s <= L_SEQ; ++s) {
      const int P = s & 1;
      float4 hv = poll4(h0s + ((s - 1) & RM) * H_DIM + (tid << 2), tagc(s - 1));
      lds4[P][tid + (tid >> 3)] = hv;
      if ((s & 3) == 0 && s >= 12 && tid < NWG1) {
        // throttle (every 4th step, overlapped): all L1 WGs >= s-11
        const float tc = tagc(s - TLAG);
        const float* tp = h1s + ((s - TLAG) & RM) * H_DIM + (tid << 4);
        while (__builtin_fabsf(cload1(tp) - tc) > 1.f) __builtin_amdgcn_s_sleep(1);
      }
      __syncthreads();
      float p0 = xp0, p1 = xp1, p2 = xp2, p3 = xp3;
      #pragma unroll
      for (int k = 0; k < 8; ++k) {      // lane's 8 f4 of h0_{s-1}, padded layout
        float4 h = lds4[P][9 * lane + k];
        p0 += dot4(whhr[k], h);
        p1 += dot4(whhr[8 + k], h);
        p2 += dot4(whhr[16 + k], h);
        p3 += dot4(whhr[24 + k], h);
      }
      #pragma unroll
      for (int m = 1; m < 64; m <<= 1) { // 64-lane reduce, 4 parallel chains
        p0 += __shfl_xor(p0, m); p1 += __shfl_xor(p1, m);
        p2 += __shfl_xor(p2, m); p3 += __shfl_xor(p3, m);
      }
      if (lane == 0) {                   // lane0 holds all 4 rows: packed publish
        const float ct = tagc(s);
        cstore4f(h0s + (s & RM) * H_DIM + r0,
                 tanh_fast(p0 + bs0) + ct, tanh_fast(p1 + bs1) + ct,
                 tanh_fast(p2 + bs2) + ct, tanh_fast(p3 + bs3) + ct);
      }
      if (s < L_SEQ) {                   // x-partials for s+1, off the serial path
        float4 xv = ((const float4*)x)[s * 64 + lane];
        xp0 = dot4(wihr[0], xv); xp1 = dot4(wihr[1], xv);
        xp2 = dot4(wihr[2], xv); xp3 = dot4(wihr[3], xv);
      }
    }

    if (wg == 0) {
      // FC: sigmoid(h1_8192 . Wfc + bfc); slot 8192&15 = 0, ctr 4.
      // Last throttle (s=8192) gave L1 >= 8181 => slot 0 holds 8176 (tag 1,
      // rejected) or 8192 (tag 0, accepted); init value long overwritten.
      float4 hv = poll4(h1s + (tid << 2), tagc(L_SEQ));
      float4 wf = ((const float4*)Wfc)[tid];
      float pz = dot4(hv, wf);
      #pragma unroll
      for (int m = 1; m < 64; m <<= 1) pz += __shfl_xor(pz, m);
      float* red = (float*)&lds4[0][0];
      __syncthreads();
      if ((tid & 63) == 0) red[wv] = pz;
      __syncthreads();
      if (tid == 0) {
        float z = bfc[0];
        #pragma unroll
        for (int w = 0; w < 8; ++w) z += red[w];
        out[0] = 1.f / (1.f + __expf(-z));
        cstoreu(runctr, runbase + 1);
      }
    }
  } else {
    // ---- layer 1: wave wv owns rows r0, r0+1; lane owns cols [32l, 32l+32) ----
    const int wgl = wg - NWG0;
    const int r0  = wgl * 16 + wv * 2;
    float4 wihr[16], whhr[16];   // [j*8+k], j in {0,1}
    {
      #pragma unroll
      for (int j = 0; j < 2; ++j) {
        const float* wr = Wih1 + (size_t)(r0 + j) * H_DIM + (lane << 5);
        #pragma unroll
        for (int k = 0; k < 8; ++k) wihr[j * 8 + k] = ld4(wr + (k << 2));
        const float* wr2 = Whh1 + (size_t)(r0 + j) * H_DIM + (lane << 5);
        #pragma unroll
        for (int k = 0; k < 8; ++k) whhr[j * 8 + k] = ld4(wr2 + (k << 2));
      }
    }
    const float ba = bih1[r0] + bhh1[r0];
    const float bb = bih1[r0 + 1] + bhh1[r0 + 1];

    if (tid < 256) {   // re-init all 16 ring slots of owned rows
      int sl = tid >> 4; int r = wgl * 16 + (tid & 15);
      cstore1(&h1s[sl * H_DIM + r], (sl == 0) ? 4.f : 0.f);
    }
    start_barrier(bslots, wg, tid, runbase + 1);

    // prologue: issue prefetch of h0_1, then force a drain so pf is complete
    f32x4 pfA;
    pf_issue(pfA, h0s + (1 & RM) * H_DIM + (tid << 2));
    (void)cloadu(runctr);   // embedded vmcnt(0) drains pfA

    for (int t = 1; t <= L_SEQ; ++t) {
      const int P = t & 1;
      const float c0 = tagc(t);
      // phase A: h0_t from prefetch (validate; poll fallback)
      pf_wait1(pfA);
      float4 a = pf_finish(pfA, h0s + (t & RM) * H_DIM + (tid << 2), c0);
      lds4[P][tid + (tid >> 3)] = a;
      if (t < L_SEQ)   // next h0 prefetch; drained by this iter's h1 poll
        pf_issue(pfA, h0s + ((t + 1) & RM) * H_DIM + (tid << 2));
      __syncthreads();
      float pa = 0.f, pb = 0.f;
      #pragma unroll
      for (int k = 0; k < 8; ++k) {      // ih dot over lane's 8 f4 of h0_t
        float4 h = lds4[P][9 * lane + k];
        pa += dot4(wihr[k], h);
        pb += dot4(wihr[8 + k], h);
      }
      // phase B: h1_{t-1} -- the critical detect, polled late (proven position)
      float4 b = poll4(h1s + ((t - 1) & RM) * H_DIM + (tid << 2), tagc(t - 1));
      lds4[P][576 + tid + (tid >> 3)] = b;
      __syncthreads();
      #pragma unroll
      for (int k = 0; k < 8; ++k) {      // hh dot over lane's 8 f4 of h1_{t-1}
        float4 h = lds4[P][576 + 9 * lane + k];
        pa += dot4(whhr[k], h);
        pb += dot4(whhr[8 + k], h);
      }
      #pragma unroll
      for (int m = 1; m < 64; m <<= 1) { // 64-lane reduce, 2 parallel chains
        pa += __shfl_xor(pa, m); pb += __shfl_xor(pb, m);
      }
      if (lane == 0) {                   // lane0 holds both rows: packed publish
        const float ct = tagc(t);
        cstore2f(h1s + (t & RM) * H_DIM + r0,
                 tanh_fast(pa + ba) + ct, tanh_fast(pb + bb) + ct);
      }
    }
  }
}

extern "C" void kernel_launch(void* const* d_in, const int* in_sizes, int n_in,
                              void* d_out, int out_size, void* d_ws, size_t ws_size,
                              hipStream_t stream) {
  const float* xx   = (const float*)d_in[0];
  const float* Wih0 = (const float*)d_in[1];
  const float* Whh0 = (const float*)d_in[2];
  const float* bih0 = (const float*)d_in[3];
  const float* bhh0 = (const float*)d_in[4];
  const float* Wih1 = (const float*)d_in[5];
  const float* Whh1 = (const float*)d_in[6];
  const float* bih1 = (const float*)d_in[7];
  const float* bhh1 = (const float*)d_in[8];
  const float* Wfc  = (const float*)d_in[9];
  const float* bfc  = (const float*)d_in[10];

  unsigned* runctr = (unsigned*)d_ws;
  unsigned* bslots = (unsigned*)((char*)d_ws + 256);
  float* h0s       = (float*)((char*)d_ws + 4096);
  float* h1s       = (float*)((char*)d_ws + 4096 + RD * H_DIM * sizeof(float));

  rnn2_colb<<<dim3(NWG), dim3(TPB), 0, stream>>>(
      xx, Wih0, Whh0, bih0, bhh0, Wih1, Whh1, bih1, bhh1, Wfc, bfc,
      (float*)d_out, runctr, bslots, h0s, h1s);
}